// Round 25
// baseline (62.011 us; speedup 1.0000x reference)
//
#include <hip/hip_runtime.h>

#define NB   8
#define ND   64
#define NP   1024
#define KDIM 128
#define HID  256
#define OUTD 256
#define CSC  2.885390081777927f   // 2*log2(e)
#define PSTR 520                  // sred plane stride (mod 32 = 8)
#define AST  264                  // a2s plane stride: >=256 j + pad (mod 32 = 8)
                                  // R24 bug: AST=132 < 256 -> plane overlap

typedef __attribute__((ext_vector_type(8))) short  bf16x8;
typedef __attribute__((ext_vector_type(4))) float  f32x4;

// E-trick: sigma = rcp(fma(Ed,Ep,1)); tanh = 1-2*sigma. EhpT transposed.
// R25 = R24 with the a2s stride bug fixed. 4-row i-blocking: every EhpT/Efp
// float4 feeds 16 sigma (vs 8) -> loads & L2 stream per sigma halve.
// Deferred norm (j in 4 quarters), comb4 (1 rcp / 4 sigma) kept.

__device__ __forceinline__ ushort f2bf(float f) {
    unsigned u = __float_as_uint(f);
    return (ushort)((u + 0x7FFFu + ((u >> 16) & 1u)) >> 16);
}

// sum_{i=1..4} c_i/u_i added to acc, one rcp (exact algebra).
__device__ __forceinline__ float comb4(float u1, float u2, float u3, float u4,
                                       float c1, float c2, float c3, float c4,
                                       float acc) {
    float p12 = u1 * u2, p34 = u3 * u4;
    float P   = p12 * p34;
    float t1  = fmaf(c1, u2, c2 * u1);
    float t2  = fmaf(c3, u4, c4 * u3);
    float num = fmaf(t1, p34, t2 * p12);
    return fmaf(num, __builtin_amdgcn_rcpf(P), acc);
}

// K0: cast X -> bf16 (k-contig); W -> bf16 TRANSPOSED (WT[n][k]).
__global__ __launch_bounds__(256) void k_cast(
    const float* __restrict__ Xd, const float* __restrict__ Xp,
    const float* __restrict__ Wd, const float* __restrict__ Wa,
    const float* __restrict__ Wp, const float* __restrict__ Wb,
    ushort* __restrict__ Xdbf, ushort* __restrict__ Xpbf,
    ushort* __restrict__ WdT, ushort* __restrict__ WaT,
    ushort* __restrict__ WpT, ushort* __restrict__ WbT) {
    int blk = blockIdx.x, t = threadIdx.x;
    if (blk < 1024) {
        size_t i = ((size_t)blk << 10) + ((size_t)t << 2);
        float4 v = *(const float4*)(Xp + i);
        ushort4 o; o.x = f2bf(v.x); o.y = f2bf(v.y); o.z = f2bf(v.z); o.w = f2bf(v.w);
        *(ushort4*)(Xpbf + i) = o;
    } else if (blk < 1088) {
        size_t i = ((size_t)(blk - 1024) << 10) + ((size_t)t << 2);
        float4 v = *(const float4*)(Xd + i);
        ushort4 o; o.x = f2bf(v.x); o.y = f2bf(v.y); o.z = f2bf(v.z); o.w = f2bf(v.w);
        *(ushort4*)(Xdbf + i) = o;
    } else {
        int r = blk - 1088, mat = r >> 5;
        const float* W = (mat == 0) ? Wd : (mat == 1) ? Wa : (mat == 2) ? Wp : Wb;
        ushort* WT = (mat == 0) ? WdT : (mat == 1) ? WaT : (mat == 2) ? WpT : WbT;
        int o0 = ((r & 31) << 10) + (t << 2);
        int n = o0 >> 7, k0 = o0 & 127;
        ushort4 o;
        o.x = f2bf(W[(k0 + 0) * HID + n]);
        o.y = f2bf(W[(k0 + 1) * HID + n]);
        o.z = f2bf(W[(k0 + 2) * HID + n]);
        o.w = f2bf(W[(k0 + 3) * HID + n]);
        *(ushort4*)(WT + o0) = o;
    }
}

// K1: MFMA projection + fused exp2 (verified absmax 0.0625).
__global__ __launch_bounds__(256) void k_proj_mfma(
    const ushort* __restrict__ Xpbf, const ushort* __restrict__ Xdbf,
    const ushort* __restrict__ WdT, const ushort* __restrict__ WaT,
    const ushort* __restrict__ WpT, const ushort* __restrict__ WbT,
    float* __restrict__ Ehd, float* __restrict__ Efd,
    float* __restrict__ EhpT, float* __restrict__ Efp) {
    int blk = blockIdx.x, t = threadIdx.x;
    const ushort *A, *B;
    float* out; size_t obase; int ostride, am0, bn0;
    if (blk < 512) {
        int mt = blk >> 2, nt = blk & 3;
        A = Xpbf; am0 = mt * 64; B = WbT; bn0 = nt * 64;
        out = Efp; obase = (size_t)am0 * HID + bn0; ostride = HID;
    } else if (blk < 1024) {
        int r = blk - 512, b = r >> 6, rr = r & 63;
        int mt = rr >> 4, nt = rr & 15;
        A = WpT; am0 = mt * 64;
        B = Xpbf + (size_t)b * NP * KDIM; bn0 = nt * 64;
        out = EhpT; obase = ((size_t)(b * 256 + am0)) * NP + bn0; ostride = NP;
    } else if (blk < 1056) {
        int r = blk - 1024; int mt = r >> 2, nt = r & 3;
        A = Xdbf; am0 = mt * 64; B = WdT; bn0 = nt * 64;
        out = Ehd; obase = (size_t)am0 * HID + bn0; ostride = HID;
    } else {
        int r = blk - 1056; int mt = r >> 2, nt = r & 3;
        A = Xdbf; am0 = mt * 64; B = WaT; bn0 = nt * 64;
        out = Efd; obase = (size_t)am0 * HID + bn0; ostride = HID;
    }
    int l = t & 63, w = t >> 6;
    int wm = (w >> 1) << 5, wn = (w & 1) << 5;
    int lr = l & 15, lk = (l >> 4) << 3;
    const ushort* Ab = A + (size_t)(am0 + wm + lr) * KDIM + lk;
    const ushort* Bb = B + (size_t)(bn0 + wn + lr) * KDIM + lk;

    bf16x8 af[2][4], bfr[2][4];
#pragma unroll
    for (int f = 0; f < 2; ++f)
#pragma unroll
        for (int ks = 0; ks < 4; ++ks) {
            af[f][ks]  = *(const bf16x8*)(Ab + (size_t)(f << 4) * KDIM + (ks << 5));
            bfr[f][ks] = *(const bf16x8*)(Bb + (size_t)(f << 4) * KDIM + (ks << 5));
        }

    f32x4 acc[2][2];
#pragma unroll
    for (int mf = 0; mf < 2; ++mf)
#pragma unroll
        for (int nf = 0; nf < 2; ++nf) acc[mf][nf] = (f32x4){0.f, 0.f, 0.f, 0.f};
#pragma unroll
    for (int ks = 0; ks < 4; ++ks)
#pragma unroll
        for (int mf = 0; mf < 2; ++mf)
#pragma unroll
            for (int nf = 0; nf < 2; ++nf)
                acc[mf][nf] = __builtin_amdgcn_mfma_f32_16x16x32_bf16(
                    af[mf][ks], bfr[nf][ks], acc[mf][nf], 0, 0, 0);

#pragma unroll
    for (int mf = 0; mf < 2; ++mf)
#pragma unroll
        for (int nf = 0; nf < 2; ++nf)
#pragma unroll
            for (int r = 0; r < 4; ++r) {
                int m = wm + (mf << 4) + ((l >> 4) << 2) + r;
                int n = wn + (nf << 4) + (l & 15);
                out[obase + (size_t)m * ostride + n] =
                    __builtin_amdgcn_exp2f(acc[mf][nf][r] * CSC);
            }
}

// K2: FUSED scores+exp+facc (deferred norm), 4 i-rows x 256-j quarter.
// grid 512 (b=blk&7, quad=(blk>>3)&15, jo=blk>>7), 512 thr, 3 blocks/CU.
// hrow4[h] = (Ehd r0..r3). Every float4 load feeds 16 sigma via comb4.
__global__ __launch_bounds__(512, 4) void k_fused(
    const float* __restrict__ Ehd, const float* __restrict__ EhpT,
    const float* __restrict__ Efd, const float* __restrict__ Efp,
    const float* __restrict__ wsc, float* __restrict__ num,
    float* __restrict__ den) {
    int blk = blockIdx.x;
    int b = blk & 7, quad = (blk >> 3) & 15, jo = blk >> 7;
    int row0 = b * ND + quad * 4;
    int t = threadIdx.x;

    __shared__ float4 hrow4[256];        // 4 KB (4 rows)
    __shared__ float  w2s[256];          // 1 KB
    __shared__ float  a2s[4 * AST];      // 4.1 KB (-2u per row, padded planes)
    __shared__ float  sred[16 * PSTR];   // 33.3 KB
    __shared__ float  wsA[8], wsB[8];

    if (t < 256) {
        hrow4[t] = make_float4(Ehd[((size_t)row0 << 8) + t],
                               Ehd[((size_t)(row0 + 1) << 8) + t],
                               Ehd[((size_t)(row0 + 2) << 8) + t],
                               Ehd[((size_t)(row0 + 3) << 8) + t]);
        w2s[t] = -2.0f * wsc[t];
    }
    __syncthreads();

    // ---- phase 1: scores, 256 j x 256 h; comb4 over h; 4 rows share loads ----
    {
        int jq = t & 63, hq = t >> 6;    // 4 j; hq 0..7 (32 h each)
        const float* pB = EhpT + ((size_t)((b << 8) + (hq << 5))) * NP
                        + (jo << 8) + (jq << 2);
        float acc[4][4];
#pragma unroll
        for (int r = 0; r < 4; ++r)
#pragma unroll
            for (int c = 0; c < 4; ++c) acc[r][c] = 0.f;
        for (int hg = 0; hg < 8; ++hg) {
            const float* pr = pB + (size_t)(hg << 2) * NP;
            float4 p0 = *(const float4*)(pr);
            float4 p1 = *(const float4*)(pr + NP);
            float4 p2 = *(const float4*)(pr + 2 * (size_t)NP);
            float4 p3 = *(const float4*)(pr + 3 * (size_t)NP);
            int h = (hq << 5) + (hg << 2);
            float4 h0 = hrow4[h],     h1 = hrow4[h + 1];
            float4 h2 = hrow4[h + 2], h3 = hrow4[h + 3];
            float w0 = w2s[h],     w1 = w2s[h + 1];
            float w2 = w2s[h + 2], w3 = w2s[h + 3];
#define ROW1(HC, AR)                                                          \
            AR[0] = comb4(fmaf(h0.HC, p0.x, 1.f), fmaf(h1.HC, p1.x, 1.f),     \
                          fmaf(h2.HC, p2.x, 1.f), fmaf(h3.HC, p3.x, 1.f),     \
                          w0, w1, w2, w3, AR[0]);                             \
            AR[1] = comb4(fmaf(h0.HC, p0.y, 1.f), fmaf(h1.HC, p1.y, 1.f),     \
                          fmaf(h2.HC, p2.y, 1.f), fmaf(h3.HC, p3.y, 1.f),     \
                          w0, w1, w2, w3, AR[1]);                             \
            AR[2] = comb4(fmaf(h0.HC, p0.z, 1.f), fmaf(h1.HC, p1.z, 1.f),     \
                          fmaf(h2.HC, p2.z, 1.f), fmaf(h3.HC, p3.z, 1.f),     \
                          w0, w1, w2, w3, AR[2]);                             \
            AR[3] = comb4(fmaf(h0.HC, p0.w, 1.f), fmaf(h1.HC, p1.w, 1.f),     \
                          fmaf(h2.HC, p2.w, 1.f), fmaf(h3.HC, p3.w, 1.f),     \
                          w0, w1, w2, w3, AR[3])
            ROW1(x, acc[0]);
            ROW1(y, acc[1]);
            ROW1(z, acc[2]);
            ROW1(w, acc[3]);
#undef ROW1
        }
        int base = (hq << 6) + jq;
#pragma unroll
        for (int r = 0; r < 4; ++r)
#pragma unroll
            for (int c = 0; c < 4; ++c)
                sred[((r << 2) + c) * PSTR + base] = acc[r][c];
    }
    __syncthreads();

    // ---- phase 2: u = e^s (unnorm), a2s = -2u, den partials ----
    {
        int j = t & 255, rh = t >> 8;    // rows 2rh, 2rh+1
        int jq2 = j >> 2, jc = j & 3;
        int rA = rh << 1, rB = rA + 1;
        const float* pA = sred + ((rA << 2) + jc) * PSTR + jq2;
        const float* pB2 = sred + ((rB << 2) + jc) * PSTR + jq2;
        float sA = 0.f, sB = 0.f;
#pragma unroll
        for (int hq = 0; hq < 8; ++hq) {
            sA += pA[hq << 6];
            sB += pB2[hq << 6];
        }
        const float L2E = 1.4426950408889634f;
        float uA = __builtin_amdgcn_exp2f(sA * L2E);
        float uB = __builtin_amdgcn_exp2f(sB * L2E);
        a2s[rA * AST + j] = -2.f * uA;
        a2s[rB * AST + j] = -2.f * uB;
        float tA = uA, tB = uB;
#pragma unroll
        for (int off = 32; off > 0; off >>= 1) {
            tA += __shfl_xor(tA, off, 64);
            tB += __shfl_xor(tB, off, 64);
        }
        if ((t & 63) == 0) { wsA[t >> 6] = tA; wsB[t >> 6] = tB; }
    }
    __syncthreads();
    if (t == 0) {
        den[((size_t)(row0 + 0) << 2) + jo] = (wsA[0] + wsA[1]) + (wsA[2] + wsA[3]);
        den[((size_t)(row0 + 1) << 2) + jo] = (wsB[0] + wsB[1]) + (wsB[2] + wsB[3]);
        den[((size_t)(row0 + 2) << 2) + jo] = (wsA[4] + wsA[5]) + (wsA[6] + wsA[7]);
        den[((size_t)(row0 + 3) << 2) + jo] = (wsB[4] + wsB[5]) + (wsB[6] + wsB[7]);
    }

    // ---- phase 3: num partials, 256 j x 256 o; comb4 over j; rows share ----
    {
        int oq = t & 63, jg = t >> 6;    // 4 o; jg 0..7 (32 j each)
        int o0 = oq << 2;
        float4 fd0 = *(const float4*)(Efd + ((size_t)row0 << 8) + o0);
        float4 fd1 = *(const float4*)(Efd + ((size_t)(row0 + 1) << 8) + o0);
        float4 fd2 = *(const float4*)(Efd + ((size_t)(row0 + 2) << 8) + o0);
        float4 fd3 = *(const float4*)(Efd + ((size_t)(row0 + 3) << 8) + o0);
        const float* fpB = Efp + ((size_t)(b * NP + (jo << 8) + (jg << 5)) << 8) + o0;
        float bcc[4][4];
#pragma unroll
        for (int r = 0; r < 4; ++r)
#pragma unroll
            for (int c = 0; c < 4; ++c) bcc[r][c] = 0.f;
        for (int g = 0; g < 8; ++g) {
            const float* fr = fpB + ((size_t)(g << 2) << 8);
            float4 f0 = *(const float4*)(fr);
            float4 f1 = *(const float4*)(fr + 256);
            float4 f2 = *(const float4*)(fr + 512);
            float4 f3 = *(const float4*)(fr + 768);
            int j0 = (jg << 5) + (g << 2);
#define ROW3(FD, RI, BR)                                                      \
            {                                                                 \
                float c0 = a2s[RI * AST + j0],     c1 = a2s[RI * AST + j0 + 1];\
                float c2 = a2s[RI * AST + j0 + 2], c3 = a2s[RI * AST + j0 + 3];\
                BR[0] = comb4(fmaf(FD.x, f0.x, 1.f), fmaf(FD.x, f1.x, 1.f),   \
                              fmaf(FD.x, f2.x, 1.f), fmaf(FD.x, f3.x, 1.f),   \
                              c0, c1, c2, c3, BR[0]);                         \
                BR[1] = comb4(fmaf(FD.y, f0.y, 1.f), fmaf(FD.y, f1.y, 1.f),   \
                              fmaf(FD.y, f2.y, 1.f), fmaf(FD.y, f3.y, 1.f),   \
                              c0, c1, c2, c3, BR[1]);                         \
                BR[2] = comb4(fmaf(FD.z, f0.z, 1.f), fmaf(FD.z, f1.z, 1.f),   \
                              fmaf(FD.z, f2.z, 1.f), fmaf(FD.z, f3.z, 1.f),   \
                              c0, c1, c2, c3, BR[2]);                         \
                BR[3] = comb4(fmaf(FD.w, f0.w, 1.f), fmaf(FD.w, f1.w, 1.f),   \
                              fmaf(FD.w, f2.w, 1.f), fmaf(FD.w, f3.w, 1.f),   \
                              c0, c1, c2, c3, BR[3]);                         \
            }
            ROW3(fd0, 0, bcc[0]);
            ROW3(fd1, 1, bcc[1]);
            ROW3(fd2, 2, bcc[2]);
            ROW3(fd3, 3, bcc[3]);
#undef ROW3
        }
        __syncthreads();                 // phase-2 sred reads done
        int base = (jg << 6) + oq;
#pragma unroll
        for (int r = 0; r < 4; ++r)
#pragma unroll
            for (int c = 0; c < 4; ++c)
                sred[((r << 2) + c) * PSTR + base] = bcc[r][c];
    }
    __syncthreads();

#pragma unroll
    for (int rh2 = 0; rh2 < 2; ++rh2) {
        int r = (t >> 8) + (rh2 << 1);   // rows 0..3
        int o = t & 255;
        const float* pk = sred + ((r << 2) + (o & 3)) * PSTR + (o >> 2);
        float s = 0.f;
#pragma unroll
        for (int g = 0; g < 8; ++g) s += pk[g << 6];
        num[((((size_t)(row0 + r) << 2) + jo) << 8) + o] = s;
    }
}

// K3: out[b][o] = 64 + sum_i num_row * rcp(den_row). grid = 8.
__global__ __launch_bounds__(256) void k_reduce(
    const float* __restrict__ num, const float* __restrict__ den,
    float* __restrict__ out) {
    int b = blockIdx.x, t = threadIdx.x;
    float s = 64.0f;
    for (int i = 0; i < 64; ++i) {
        size_t row = (size_t)(b * 64 + i);
        float D = (den[(row << 2) + 0] + den[(row << 2) + 1]) +
                  (den[(row << 2) + 2] + den[(row << 2) + 3]);
        const float* nb = num + (row << 10) + t;
        float n = (nb[0] + nb[256]) + (nb[512] + nb[768]);
        s += n * __builtin_amdgcn_rcpf(D);
    }
    out[(b << 8) + t] = s;
}

extern "C" void kernel_launch(void* const* d_in, const int* in_sizes, int n_in,
                              void* d_out, int out_size, void* d_ws, size_t ws_size,
                              hipStream_t stream) {
    const float* Xd  = (const float*)d_in[0];
    const float* Xp  = (const float*)d_in[1];
    const float* Wd  = (const float*)d_in[2];
    const float* Wp  = (const float*)d_in[3];
    const float* Wa  = (const float*)d_in[4];
    const float* Wb  = (const float*)d_in[5];
    const float* wsc = (const float*)d_in[6];
    float* out = (float*)d_out;

    float* ws = (float*)d_ws;
    float* Ehd  = ws;                         // 131072 f
    float* Efd  = Ehd + NB * ND * HID;        // 131072 f
    float* EhpT = Efd + NB * ND * OUTD;       // 2097152 f
    float* Efp  = EhpT + NB * NP * HID;       // 2097152 f
    float* stage = Efp + NB * NP * OUTD;      // bf16 staging region (622592 f)
    ushort* Xpbf = (ushort*)stage;
    ushort* Xdbf = Xpbf + NB * NP * KDIM;
    ushort* WdT  = Xdbf + 65536;
    ushort* WaT  = WdT + 32768;
    ushort* WpT  = WaT + 32768;
    ushort* WbT  = WpT + 32768;
    float* numb = stage;                      // 524288 f — overlays dead staging
    float* denb = stage + 622592;             // 2048 f

    k_cast     <<<1216, 256, 0, stream>>>(Xd, Xp, Wd, Wa, Wp, Wb,
                                          Xdbf, Xpbf, WdT, WaT, WpT, WbT);
    k_proj_mfma<<<1088, 256, 0, stream>>>(Xpbf, Xdbf, WdT, WaT, WpT, WbT,
                                          Ehd, Efd, EhpT, Efp);
    k_fused    <<<512, 512, 0, stream>>>(Ehd, EhpT, Efd, Efp, wsc, numb, denb);
    k_reduce   <<<NB, 256, 0, stream>>>(numb, denb, out);
}

// Round 26
// 59.534 us; speedup vs baseline: 1.0416x; 1.0416x over previous
//
#include <hip/hip_runtime.h>

#define NB   8
#define ND   64
#define NP   1024
#define KDIM 128
#define HID  256
#define OUTD 256
#define CSC  2.885390081777927f   // 2*log2(e)
#define PSTR 1048                 // sred plane stride: !=0 mod 32

typedef __attribute__((ext_vector_type(8))) short  bf16x8;
typedef __attribute__((ext_vector_type(4))) float  f32x4;

// FINAL (revert to R21, best measured 59.1us):
// E-trick: sigma = rcp(fma(Ed,Ep,1)); tanh = 1-2*sigma. EhpT transposed.
// comb4: sum_i c_i/u_i = [t1*p34+t2*p12]*rcp(p12*p34) -> 1 rcp per 4 sigma
// (9cy/elem vs 12). Fused scores+softmax+facc per 2-row block. MFMA bf16
// projections. Falsified alternatives: TLP splits (R20/R23), reg prefetch
// (R17/R19), DMA staging (R18), 4-row blocking (R25) -- all neutral/worse.

__device__ __forceinline__ ushort f2bf(float f) {
    unsigned u = __float_as_uint(f);
    return (ushort)((u + 0x7FFFu + ((u >> 16) & 1u)) >> 16);
}

// sum_{i=1..4} c_i/u_i added to acc, one rcp (exact algebra).
__device__ __forceinline__ float comb4(float u1, float u2, float u3, float u4,
                                       float c1, float c2, float c3, float c4,
                                       float acc) {
    float p12 = u1 * u2, p34 = u3 * u4;
    float P   = p12 * p34;
    float t1  = fmaf(c1, u2, c2 * u1);
    float t2  = fmaf(c3, u4, c4 * u3);
    float num = fmaf(t1, p34, t2 * p12);
    return fmaf(num, __builtin_amdgcn_rcpf(P), acc);
}

// K0: cast X -> bf16 (k-contig); W -> bf16 TRANSPOSED (WT[n][k]).
__global__ __launch_bounds__(256) void k_cast(
    const float* __restrict__ Xd, const float* __restrict__ Xp,
    const float* __restrict__ Wd, const float* __restrict__ Wa,
    const float* __restrict__ Wp, const float* __restrict__ Wb,
    ushort* __restrict__ Xdbf, ushort* __restrict__ Xpbf,
    ushort* __restrict__ WdT, ushort* __restrict__ WaT,
    ushort* __restrict__ WpT, ushort* __restrict__ WbT) {
    int blk = blockIdx.x, t = threadIdx.x;
    if (blk < 1024) {
        size_t i = ((size_t)blk << 10) + ((size_t)t << 2);
        float4 v = *(const float4*)(Xp + i);
        ushort4 o; o.x = f2bf(v.x); o.y = f2bf(v.y); o.z = f2bf(v.z); o.w = f2bf(v.w);
        *(ushort4*)(Xpbf + i) = o;
    } else if (blk < 1088) {
        size_t i = ((size_t)(blk - 1024) << 10) + ((size_t)t << 2);
        float4 v = *(const float4*)(Xd + i);
        ushort4 o; o.x = f2bf(v.x); o.y = f2bf(v.y); o.z = f2bf(v.z); o.w = f2bf(v.w);
        *(ushort4*)(Xdbf + i) = o;
    } else {
        int r = blk - 1088, mat = r >> 5;
        const float* W = (mat == 0) ? Wd : (mat == 1) ? Wa : (mat == 2) ? Wp : Wb;
        ushort* WT = (mat == 0) ? WdT : (mat == 1) ? WaT : (mat == 2) ? WpT : WbT;
        int o0 = ((r & 31) << 10) + (t << 2);
        int n = o0 >> 7, k0 = o0 & 127;
        ushort4 o;
        o.x = f2bf(W[(k0 + 0) * HID + n]);
        o.y = f2bf(W[(k0 + 1) * HID + n]);
        o.z = f2bf(W[(k0 + 2) * HID + n]);
        o.w = f2bf(W[(k0 + 3) * HID + n]);
        *(ushort4*)(WT + o0) = o;
    }
}

// K1: MFMA projection + fused exp2 (verified absmax 0.0625).
__global__ __launch_bounds__(256) void k_proj_mfma(
    const ushort* __restrict__ Xpbf, const ushort* __restrict__ Xdbf,
    const ushort* __restrict__ WdT, const ushort* __restrict__ WaT,
    const ushort* __restrict__ WpT, const ushort* __restrict__ WbT,
    float* __restrict__ Ehd, float* __restrict__ Efd,
    float* __restrict__ EhpT, float* __restrict__ Efp) {
    int blk = blockIdx.x, t = threadIdx.x;
    const ushort *A, *B;
    float* out; size_t obase; int ostride, am0, bn0;
    if (blk < 512) {
        int mt = blk >> 2, nt = blk & 3;
        A = Xpbf; am0 = mt * 64; B = WbT; bn0 = nt * 64;
        out = Efp; obase = (size_t)am0 * HID + bn0; ostride = HID;
    } else if (blk < 1024) {
        int r = blk - 512, b = r >> 6, rr = r & 63;
        int mt = rr >> 4, nt = rr & 15;
        A = WpT; am0 = mt * 64;
        B = Xpbf + (size_t)b * NP * KDIM; bn0 = nt * 64;
        out = EhpT; obase = ((size_t)(b * 256 + am0)) * NP + bn0; ostride = NP;
    } else if (blk < 1056) {
        int r = blk - 1024; int mt = r >> 2, nt = r & 3;
        A = Xdbf; am0 = mt * 64; B = WdT; bn0 = nt * 64;
        out = Ehd; obase = (size_t)am0 * HID + bn0; ostride = HID;
    } else {
        int r = blk - 1056; int mt = r >> 2, nt = r & 3;
        A = Xdbf; am0 = mt * 64; B = WaT; bn0 = nt * 64;
        out = Efd; obase = (size_t)am0 * HID + bn0; ostride = HID;
    }
    int l = t & 63, w = t >> 6;
    int wm = (w >> 1) << 5, wn = (w & 1) << 5;
    int lr = l & 15, lk = (l >> 4) << 3;
    const ushort* Ab = A + (size_t)(am0 + wm + lr) * KDIM + lk;
    const ushort* Bb = B + (size_t)(bn0 + wn + lr) * KDIM + lk;

    bf16x8 af[2][4], bfr[2][4];
#pragma unroll
    for (int f = 0; f < 2; ++f)
#pragma unroll
        for (int ks = 0; ks < 4; ++ks) {
            af[f][ks]  = *(const bf16x8*)(Ab + (size_t)(f << 4) * KDIM + (ks << 5));
            bfr[f][ks] = *(const bf16x8*)(Bb + (size_t)(f << 4) * KDIM + (ks << 5));
        }

    f32x4 acc[2][2];
#pragma unroll
    for (int mf = 0; mf < 2; ++mf)
#pragma unroll
        for (int nf = 0; nf < 2; ++nf) acc[mf][nf] = (f32x4){0.f, 0.f, 0.f, 0.f};
#pragma unroll
    for (int ks = 0; ks < 4; ++ks)
#pragma unroll
        for (int mf = 0; mf < 2; ++mf)
#pragma unroll
            for (int nf = 0; nf < 2; ++nf)
                acc[mf][nf] = __builtin_amdgcn_mfma_f32_16x16x32_bf16(
                    af[mf][ks], bfr[nf][ks], acc[mf][nf], 0, 0, 0);

#pragma unroll
    for (int mf = 0; mf < 2; ++mf)
#pragma unroll
        for (int nf = 0; nf < 2; ++nf)
#pragma unroll
            for (int r = 0; r < 4; ++r) {
                int m = wm + (mf << 4) + ((l >> 4) << 2) + r;
                int n = wn + (nf << 4) + (l & 15);
                out[obase + (size_t)m * ostride + n] =
                    __builtin_amdgcn_exp2f(acc[mf][nf][r] * CSC);
            }
}

// K2: FUSED scores+softmax+facc, 2 i-rows/block, grid 256, 1024 thr.
// Inner loops use 4-way reciprocal batching (comb4): 1 rcp per 4 sigma.
__global__ __launch_bounds__(1024, 4) void k_fused(
    const float* __restrict__ Ehd, const float* __restrict__ EhpT,
    const float* __restrict__ Efd, const float* __restrict__ Efp,
    const float* __restrict__ wsc, float* __restrict__ part) {
    int blk = blockIdx.x;
    int b = blk & 7, pair = blk >> 3;
    int row0 = b * ND + pair * 2;
    int t = threadIdx.x;

    __shared__ float2 hrow[256];
    __shared__ float  w2s[256];
    __shared__ float2 a2[1024];
    __shared__ float  sred[8 * PSTR];
    __shared__ float  wsum0[16], wsum1[16];

    if (t < 256) {
        hrow[t] = make_float2(Ehd[((size_t)row0 << 8) + t],
                              Ehd[((size_t)(row0 + 1) << 8) + t]);
        w2s[t] = -2.0f * wsc[t];
    }
    __syncthreads();

    // ---- phase 1: scores, 4 h combined per rcp ----
    {
        int jq = t & 255, hq = t >> 8;
        const float* pB = EhpT + ((size_t)((b << 8) + (hq << 6))) * NP + (jq << 2);
        float a00 = 0, a01 = 0, a02 = 0, a03 = 0;
        float a10 = 0, a11 = 0, a12 = 0, a13 = 0;
        for (int hg = 0; hg < 16; ++hg) {
            const float* pr = pB + (size_t)(hg << 2) * NP;
            float4 p0 = *(const float4*)(pr);
            float4 p1 = *(const float4*)(pr + NP);
            float4 p2 = *(const float4*)(pr + 2 * (size_t)NP);
            float4 p3 = *(const float4*)(pr + 3 * (size_t)NP);
            int h = (hq << 6) + (hg << 2);
            float2 h0 = hrow[h],     h1 = hrow[h + 1];
            float2 h2 = hrow[h + 2], h3 = hrow[h + 3];
            float w0 = w2s[h],     w1 = w2s[h + 1];
            float w2 = w2s[h + 2], w3 = w2s[h + 3];
            a00 = comb4(fmaf(h0.x, p0.x, 1.f), fmaf(h1.x, p1.x, 1.f),
                        fmaf(h2.x, p2.x, 1.f), fmaf(h3.x, p3.x, 1.f),
                        w0, w1, w2, w3, a00);
            a01 = comb4(fmaf(h0.x, p0.y, 1.f), fmaf(h1.x, p1.y, 1.f),
                        fmaf(h2.x, p2.y, 1.f), fmaf(h3.x, p3.y, 1.f),
                        w0, w1, w2, w3, a01);
            a02 = comb4(fmaf(h0.x, p0.z, 1.f), fmaf(h1.x, p1.z, 1.f),
                        fmaf(h2.x, p2.z, 1.f), fmaf(h3.x, p3.z, 1.f),
                        w0, w1, w2, w3, a02);
            a03 = comb4(fmaf(h0.x, p0.w, 1.f), fmaf(h1.x, p1.w, 1.f),
                        fmaf(h2.x, p2.w, 1.f), fmaf(h3.x, p3.w, 1.f),
                        w0, w1, w2, w3, a03);
            a10 = comb4(fmaf(h0.y, p0.x, 1.f), fmaf(h1.y, p1.x, 1.f),
                        fmaf(h2.y, p2.x, 1.f), fmaf(h3.y, p3.x, 1.f),
                        w0, w1, w2, w3, a10);
            a11 = comb4(fmaf(h0.y, p0.y, 1.f), fmaf(h1.y, p1.y, 1.f),
                        fmaf(h2.y, p2.y, 1.f), fmaf(h3.y, p3.y, 1.f),
                        w0, w1, w2, w3, a11);
            a12 = comb4(fmaf(h0.y, p0.z, 1.f), fmaf(h1.y, p1.z, 1.f),
                        fmaf(h2.y, p2.z, 1.f), fmaf(h3.y, p3.z, 1.f),
                        w0, w1, w2, w3, a12);
            a13 = comb4(fmaf(h0.y, p0.w, 1.f), fmaf(h1.y, p1.w, 1.f),
                        fmaf(h2.y, p2.w, 1.f), fmaf(h3.y, p3.w, 1.f),
                        w0, w1, w2, w3, a13);
        }
        int base = (hq << 8) + jq;
        sred[0 * PSTR + base] = a00;  sred[1 * PSTR + base] = a01;
        sred[2 * PSTR + base] = a02;  sred[3 * PSTR + base] = a03;
        sred[4 * PSTR + base] = a10;  sred[5 * PSTR + base] = a11;
        sred[6 * PSTR + base] = a12;  sred[7 * PSTR + base] = a13;
    }
    __syncthreads();

    // ---- phase 2: softmax (no max pass: |S| <= 2*sum|w| ~ 32, fp32-safe) ----
    {
        int jq2 = t >> 2, c = t & 3;
        const float* p0 = sred + c * PSTR + jq2;
        const float* p1 = sred + (4 + c) * PSTR + jq2;
        float sc0 = (p0[0] + p0[256]) + (p0[512] + p0[768]);
        float sc1 = (p1[0] + p1[256]) + (p1[512] + p1[768]);
        const float L2E = 1.4426950408889634f;
        float e0 = __builtin_amdgcn_exp2f(sc0 * L2E);
        float e1 = __builtin_amdgcn_exp2f(sc1 * L2E);
        float s0 = e0, s1 = e1;
#pragma unroll
        for (int off = 32; off > 0; off >>= 1) {
            s0 += __shfl_xor(s0, off, 64);
            s1 += __shfl_xor(s1, off, 64);
        }
        if ((t & 63) == 0) { wsum0[t >> 6] = s0; wsum1[t >> 6] = s1; }
        __syncthreads();
        float tot0 = 0.f, tot1 = 0.f;
#pragma unroll
        for (int w = 0; w < 16; ++w) { tot0 += wsum0[w]; tot1 += wsum1[w]; }
        float sn0 = -2.0f * __builtin_amdgcn_rcpf(tot0);
        float sn1 = -2.0f * __builtin_amdgcn_rcpf(tot1);
        a2[t] = make_float2(e0 * sn0, e1 * sn1);
    }
    __syncthreads();

    // ---- phase 3: facc, 4 j combined per rcp ----
    {
        int oq = t & 63, jg = t >> 6;
        int o0 = oq << 2;
        float4 fd0 = *(const float4*)(Efd + ((size_t)row0 << 8) + o0);
        float4 fd1 = *(const float4*)(Efd + ((size_t)(row0 + 1) << 8) + o0);
        const float* fpB = Efp + ((size_t)(b * NP + (jg << 6)) << 8) + o0;
        float b00 = 0, b01 = 0, b02 = 0, b03 = 0;
        float b10 = 0, b11 = 0, b12 = 0, b13 = 0;
        for (int g = 0; g < 16; ++g) {
            const float* fr = fpB + ((size_t)(g << 2) << 8);
            float4 f0 = *(const float4*)(fr);
            float4 f1 = *(const float4*)(fr + 256);
            float4 f2 = *(const float4*)(fr + 512);
            float4 f3 = *(const float4*)(fr + 768);
            int j0 = (jg << 6) + (g << 2);
            float2 A0 = a2[j0],     A1 = a2[j0 + 1];
            float2 A2v = a2[j0 + 2], A3 = a2[j0 + 3];
            b00 = comb4(fmaf(fd0.x, f0.x, 1.f), fmaf(fd0.x, f1.x, 1.f),
                        fmaf(fd0.x, f2.x, 1.f), fmaf(fd0.x, f3.x, 1.f),
                        A0.x, A1.x, A2v.x, A3.x, b00);
            b01 = comb4(fmaf(fd0.y, f0.y, 1.f), fmaf(fd0.y, f1.y, 1.f),
                        fmaf(fd0.y, f2.y, 1.f), fmaf(fd0.y, f3.y, 1.f),
                        A0.x, A1.x, A2v.x, A3.x, b01);
            b02 = comb4(fmaf(fd0.z, f0.z, 1.f), fmaf(fd0.z, f1.z, 1.f),
                        fmaf(fd0.z, f2.z, 1.f), fmaf(fd0.z, f3.z, 1.f),
                        A0.x, A1.x, A2v.x, A3.x, b02);
            b03 = comb4(fmaf(fd0.w, f0.w, 1.f), fmaf(fd0.w, f1.w, 1.f),
                        fmaf(fd0.w, f2.w, 1.f), fmaf(fd0.w, f3.w, 1.f),
                        A0.x, A1.x, A2v.x, A3.x, b03);
            b10 = comb4(fmaf(fd1.x, f0.x, 1.f), fmaf(fd1.x, f1.x, 1.f),
                        fmaf(fd1.x, f2.x, 1.f), fmaf(fd1.x, f3.x, 1.f),
                        A0.y, A1.y, A2v.y, A3.y, b10);
            b11 = comb4(fmaf(fd1.y, f0.y, 1.f), fmaf(fd1.y, f1.y, 1.f),
                        fmaf(fd1.y, f2.y, 1.f), fmaf(fd1.y, f3.y, 1.f),
                        A0.y, A1.y, A2v.y, A3.y, b11);
            b12 = comb4(fmaf(fd1.z, f0.z, 1.f), fmaf(fd1.z, f1.z, 1.f),
                        fmaf(fd1.z, f2.z, 1.f), fmaf(fd1.z, f3.z, 1.f),
                        A0.y, A1.y, A2v.y, A3.y, b12);
            b13 = comb4(fmaf(fd1.w, f0.w, 1.f), fmaf(fd1.w, f1.w, 1.f),
                        fmaf(fd1.w, f2.w, 1.f), fmaf(fd1.w, f3.w, 1.f),
                        A0.y, A1.y, A2v.y, A3.y, b13);
        }
        __syncthreads();                 // phase-2 sred reads done
        int base = (jg << 6) + oq;
        sred[0 * PSTR + base] = b00;  sred[1 * PSTR + base] = b01;
        sred[2 * PSTR + base] = b02;  sred[3 * PSTR + base] = b03;
        sred[4 * PSTR + base] = b10;  sred[5 * PSTR + base] = b11;
        sred[6 * PSTR + base] = b12;  sred[7 * PSTR + base] = b13;
    }
    __syncthreads();

    if (t < 512) {
        int r = t >> 8, o = t & 255;
        int oq2 = o >> 2, c2 = o & 3;
        const float* pk = sred + (r * 4 + c2) * PSTR + oq2;
        float s = 0.f;
#pragma unroll
        for (int g = 0; g < 16; ++g) s += pk[g << 6];
        part[((size_t)((b << 6) + (pair << 1) + r) << 8) + o] = s;
    }
}

// K3: out[b][o] = 64 + sum over 64 i-rows. grid = 8. part layout [b][i][o].
__global__ __launch_bounds__(256) void k_reduce(
    const float* __restrict__ part, float* __restrict__ out) {
    int b = blockIdx.x, t = threadIdx.x;
    float s = 64.0f;
#pragma unroll 8
    for (int i = 0; i < 64; ++i)
        s += part[((size_t)((b << 6) + i) << 8) + t];
    out[(b << 8) + t] = s;
}

extern "C" void kernel_launch(void* const* d_in, const int* in_sizes, int n_in,
                              void* d_out, int out_size, void* d_ws, size_t ws_size,
                              hipStream_t stream) {
    const float* Xd  = (const float*)d_in[0];
    const float* Xp  = (const float*)d_in[1];
    const float* Wd  = (const float*)d_in[2];
    const float* Wp  = (const float*)d_in[3];
    const float* Wa  = (const float*)d_in[4];
    const float* Wb  = (const float*)d_in[5];
    const float* wsc = (const float*)d_in[6];
    float* out = (float*)d_out;

    float* ws = (float*)d_ws;
    float* Ehd  = ws;
    float* Efd  = Ehd + NB * ND * HID;
    float* EhpT = Efd + NB * ND * OUTD;
    float* Efp  = EhpT + NB * NP * HID;
    float* stage = Efp + NB * NP * OUTD;
    ushort* Xpbf = (ushort*)stage;
    ushort* Xdbf = Xpbf + NB * NP * KDIM;
    ushort* WdT  = Xdbf + 65536;
    ushort* WaT  = WdT + 32768;
    ushort* WpT  = WaT + 32768;
    ushort* WbT  = WpT + 32768;
    float* part  = stage;

    k_cast     <<<1216, 256, 0, stream>>>(Xd, Xp, Wd, Wa, Wp, Wb,
                                          Xdbf, Xpbf, WdT, WaT, WpT, WbT);
    k_proj_mfma<<<1088, 256, 0, stream>>>(Xpbf, Xdbf, WdT, WaT, WpT, WbT,
                                          Ehd, Efd, EhpT, Efp);
    k_fused    <<<256, 1024, 0, stream>>>(Ehd, EhpT, Efd, Efp, wsc, part);
    k_reduce   <<<NB, 256, 0, stream>>>(part, out);
}